// Round 1
// 481.747 us; speedup vs baseline: 1.3046x; 1.3046x over previous
//
#include <hip/hip_runtime.h>

// ResidualVQ: Q=4, N_EMBED=1024, DIM=256, B=8, S=2048 (fp32).
// out = [quantized 8*2048*256][indices-as-float 4*8*2048][losses 4]
//
// R13: FUSED 4-stage kernel. Rows are independent across all stages, so each
// block keeps its 16 rows of fp32 residual in LDS for the whole kernel:
//  - resid NEVER goes to global (kills 4x(16.7MB write + 16.7MB read) HBM
//    round-trips + the intra-stage triple re-read; frees L2 for cb16)
//  - av (frozen np pairwise sumsq) distributed over 32 lanes/row with an
//    exact-pairing shuffle tree -> BIT-IDENTICAL to scalar np_sumsq_256
//    (was: 16 threads x 256 weakly-pipelined scalar global loads = the
//    dominant latency-serial phase per the all-idle counters)
//  - k_init/k_final eliminated (x read once, out_q = x - residF epilogue);
//    k_b parallelized the same 32-lane way
// Certified exact re-rank structure (R11/R12) UNCHANGED: bf16-MFMA prefilter,
// tau margin with 8x slack, frozen np fp32 distance chain, tie -> lower index,
// frozen STE recursion. Values of every frozen op are bit-identical to R12.
#define QQ   4
#define NE   1024
#define DIMD 256
#define MM   16384
#define TM   16
#define NW   8      // waves per block (512 threads)
#define CAP  32     // candidate slots per row (TM*CAP == 512)

typedef short v8s __attribute__((ext_vector_type(8)));   // 8 x bf16
typedef float v4f __attribute__((ext_vector_type(4)));

// ws layout (float offsets):
//  cb16  [QQ][NE][DIMD] ushort @ 0        (524,288 floats)
//  bK    [QQ][NE]              @ 524,288  (4,096)
//  bmaxI int[QQ]               @ 528,384  (4)
//  loss64 double[QQ]           @ 528,390  (byte 2,113,560 %8==0)

__device__ __forceinline__ unsigned short f2bf(float f) {  // RNE fp32->bf16
  unsigned u = __float_as_uint(f);
  return (unsigned short)((u + 0x7FFFu + ((u >> 16) & 1u)) >> 16);
}

// FROZEN numpy (AVX-512 dispatch) pairwise sumsq of 256 f32, distributed over
// a 32-aligned group of 32 lanes (j = lane-in-group). Valid on j==0.
// Identical op tree & pairing as the scalar version: lane(bi,L) computes w[L]
// of block bi; u[L]=w[L]+w[L+8]; t=u[L]+u[L+4]; r2=t[L]+t[L+2]; blk=r2[0]+r2[1];
// total = blk[0]+blk[1]. Every __fadd_rn has the same operands -> bit-exact.
__device__ __forceinline__ float np_sumsq_256_x32(const float* __restrict__ p,
                                                  int j) {
  const int bi = j >> 4, L = j & 15;
  const float* q = p + bi * 128 + L;
  float s0 = __fmul_rn(q[0], q[0]);
  float s1 = __fmul_rn(q[16], q[16]);
  float s2 = __fmul_rn(q[32], q[32]);
  float s3 = __fmul_rn(q[48], q[48]);
  float s4 = __fmul_rn(q[64], q[64]);
  float s5 = __fmul_rn(q[80], q[80]);
  float s6 = __fmul_rn(q[96], q[96]);
  float s7 = __fmul_rn(q[112], q[112]);
  float w = __fadd_rn(__fadd_rn(__fadd_rn(s0, s1), __fadd_rn(s2, s3)),
                      __fadd_rn(__fadd_rn(s4, s5), __fadd_rn(s6, s7)));
  float u  = __fadd_rn(w,  __shfl_down(w, 8, 64));   // valid L<8
  float t  = __fadd_rn(u,  __shfl_down(u, 4, 64));   // valid L<4
  float r2 = __fadd_rn(t,  __shfl_down(t, 2, 64));   // valid L<2
  float bb = __fadd_rn(r2, __shfl_down(r2, 1, 64));  // valid L==0 -> blk[bi]
  return __fadd_rn(bb, __shfl_down(bb, 16, 64));     // valid j==0
}

// frozen np distance, float4-load pipelined (IDENTICAL fma sequence/order)
__device__ __forceinline__ float np_dist_f4(const float* __restrict__ xp,
                                            const float* __restrict__ ep,
                                            float a, float b) {
  float m = 0.f;
  #pragma unroll 16
  for (int d4 = 0; d4 < DIMD / 4; ++d4) {
    const float4 xv = *(const float4*)(xp + d4 * 4);
    const float4 ev = *(const float4*)(ep + d4 * 4);
    m = fmaf(xv.x, ev.x, m);
    m = fmaf(xv.y, ev.y, m);
    m = fmaf(xv.z, ev.z, m);
    m = fmaf(xv.w, ev.w, m);
  }
  return __fadd_rn(__fsub_rn(a, __fmul_rn(2.0f, m)), b);
}

// convert all codebooks to bf16 (RNE); block 0 also zero-inits loss/bmax
// (stream-ordered before k_b / k_fused, so no race)
__global__ __launch_bounds__(256) void k_cb16(const float* __restrict__ cb,
                                              unsigned short* __restrict__ cb16,
                                              double* __restrict__ loss64,
                                              int* __restrict__ bmaxI) {
  int i = (blockIdx.x * 256 + threadIdx.x) * 4;
  float4 f = *(const float4*)(cb + i);
  unsigned short t[4] = {f2bf(f.x), f2bf(f.y), f2bf(f.z), f2bf(f.w)};
  *(short4*)(cb16 + i) = *(short4*)t;
  if (blockIdx.x == 0 && threadIdx.x < QQ) {
    loss64[threadIdx.x] = 0.0;
    bmaxI[threadIdx.x] = 0;
  }
}

// b_k (frozen np sumsq, now 32 lanes/row) + per-stage max
__global__ __launch_bounds__(256) void k_b(const float* __restrict__ cb,
                                           float* __restrict__ bK,
                                           int* __restrict__ bmaxI) {
  int g = blockIdx.x * 256 + threadIdx.x;   // 0 .. QQ*NE*32-1
  int row = g >> 5, j = g & 31;
  float b = np_sumsq_256_x32(cb + (size_t)row * DIMD, j);
  if (j == 0) {
    bK[row] = b;
    atomicMax(bmaxI + (row >> 10), __float_as_int(b));
  }
}

// 512 threads = 8 waves; block owns TM=16 rows through ALL 4 stages.
// Wave w covers codes [w*128,(w+1)*128) as 8 16x16 MFMA col-tiles per stage.
__global__ __launch_bounds__(512, 4) void k_fused(
    const float* __restrict__ x,              // [MM][DIMD]
    const unsigned short* __restrict__ cb16a, // [QQ][NE][DIMD] bf16
    const float* __restrict__ cba,            // [QQ][NE][DIMD] fp32
    const float* __restrict__ bKa,            // [QQ][NE]
    const int*   __restrict__ bmaxI,          // [QQ]
    double* __restrict__ loss64,              // [QQ]
    float* __restrict__ out_q,                // [MM][DIMD]
    float* __restrict__ idx_out) {            // [QQ][MM] floats
  __shared__ float residF[TM][DIMD];           // fp32 residual, lives all 4 stages
  __shared__ unsigned short sX[TM][DIMD + 8];  // bf16 rows, +8 pad vs conflicts
  __shared__ float  av_s[TM];
  __shared__ float  candD[TM][NW];
  __shared__ float  thrS[TM];
  __shared__ int    cnt[TM];
  __shared__ int    candL[TM][CAP];
  __shared__ float  dcD[TM][CAP];
  __shared__ int    bcode[TM];
  __shared__ float  fwD[NW];
  __shared__ int    fwI[NW];
  __shared__ double lossW[NW];

  const int tid  = threadIdx.x;
  const int lane = tid & 63;
  const int wv   = tid >> 6;
  const int rowBase = blockIdx.x * TM;
  const int r32 = tid >> 5;        // row 0..15 (32 threads per row)
  const int j32 = tid & 31;        // lane in row-group
  const int d0  = j32 * 8;         // 8 floats per thread per row
  const int m16  = lane & 15;
  const int quad = lane >> 4;

  // x -> residF (exact fp32; stage-0 residual == x, as k_init did)
  {
    const float* xp = x + (size_t)(rowBase + r32) * DIMD + d0;
    *(float4*)&residF[r32][d0]     = *(const float4*)xp;
    *(float4*)&residF[r32][d0 + 4] = *(const float4*)(xp + 4);
  }
  __syncthreads();

  #pragma unroll 1
  for (int qi = 0; qi < QQ; ++qi) {
    const unsigned short* cb16 = cb16a + (size_t)qi * NE * DIMD;
    const float* cb = cba + (size_t)qi * NE * DIMD;
    const float* bK = bKa + (size_t)qi * NE;
    const float bmx = __int_as_float(bmaxI[qi]);

    // av (FROZEN, 32-lane parallel, from LDS) + cnt reset + bf16 staging
    {
      float av = np_sumsq_256_x32(&residF[r32][0], j32);
      if (j32 == 0) av_s[r32] = av;
    }
    if (tid < TM) cnt[tid] = 0;
    {
      const float* rp = &residF[r32][d0];
      const float4 f0 = *(const float4*)rp;
      const float4 f1 = *(const float4*)(rp + 4);
      unsigned short t[8] = {f2bf(f0.x), f2bf(f0.y), f2bf(f0.z), f2bf(f0.w),
                             f2bf(f1.x), f2bf(f1.y), f2bf(f1.z), f2bf(f1.w)};
      *(v8s*)&sX[r32][d0] = *(v8s*)t;
    }
    __syncthreads();

    // MFMA: M~[row][code] for 8 col-tiles; A from LDS, B from cb16 (row-major)
    v4f acc[8];
    #pragma unroll
    for (int ct = 0; ct < 8; ++ct) acc[ct] = (v4f)(0.f);
    const unsigned short* bptr =
        cb16 + ((size_t)(wv * 128 + m16)) * DIMD + quad * 8;
    #pragma unroll
    for (int kc = 0; kc < 8; ++kc) {
      v8s afr = *(const v8s*)&sX[m16][kc * 32 + quad * 8];
      #pragma unroll
      for (int ct = 0; ct < 8; ++ct) {
        v8s bfr = *(const v8s*)(bptr + (size_t)ct * 16 * DIMD + kc * 32);
        acc[ct] = __builtin_amdgcn_mfma_f32_16x16x32_bf16(afr, bfr, acc[ct], 0, 0, 0);
      }
    }

    // approx dist in-place: d~ = a - 2*M~ + b   (D: row=quad*4+reg, col=m16)
    float av4[4];
    #pragma unroll
    for (int v = 0; v < 4; ++v) av4[v] = av_s[quad * 4 + v];
    #pragma unroll
    for (int ct = 0; ct < 8; ++ct) {
      const float bv = bK[wv * 128 + ct * 16 + m16];
      #pragma unroll
      for (int v = 0; v < 4; ++v) acc[ct][v] = av4[v] - 2.0f * acc[ct][v] + bv;
    }

    // per-row min: over ct, then across the 16 lanes of each quad
    float vmin[4];
    #pragma unroll
    for (int v = 0; v < 4; ++v) {
      vmin[v] = acc[0][v];
      #pragma unroll
      for (int ct = 1; ct < 8; ++ct) vmin[v] = fminf(vmin[v], acc[ct][v]);
      #pragma unroll
      for (int off = 1; off < 16; off <<= 1)
        vmin[v] = fminf(vmin[v], __shfl_xor(vmin[v], off, 64));
    }
    if (m16 == 0) {
      #pragma unroll
      for (int v = 0; v < 4; ++v) candD[quad * 4 + v][wv] = vmin[v];
    }
    __syncthreads();
    if (tid < TM) {
      float bd = candD[tid][0];
      #pragma unroll
      for (int w = 1; w < NW; ++w) bd = fminf(bd, candD[tid][w]);
      // certified margin: 2*2^-8*sqrt(a*bmax) needed; 2^-5*sqrt(.)+0.1 = 8x slack
      thrS[tid] = bd + 0.03125f * sqrtf(av_s[tid] * bmx) + 0.1f;
    }
    __syncthreads();

    // gather candidates
    #pragma unroll
    for (int ct = 0; ct < 8; ++ct) {
      const int code = wv * 128 + ct * 16 + m16;
      #pragma unroll
      for (int v = 0; v < 4; ++v) {
        const int row = quad * 4 + v;
        if (acc[ct][v] <= thrS[row]) {
          int pos = atomicAdd(&cnt[row], 1);
          if (pos < CAP) candL[row][pos] = code;
        }
      }
    }
    __syncthreads();

    // exact (frozen) distance per candidate: one thread per (row, slot);
    // x-row comes from LDS (identical fp32 values; identical fma order)
    {
      const int n = (cnt[r32] <= CAP) ? cnt[r32] : 0;  // overflow -> fallback
      if (j32 < n) {
        const int code = candL[r32][j32];
        dcD[r32][j32] = np_dist_f4(&residF[r32][0], cb + (size_t)code * DIMD,
                                   av_s[r32], bK[code]);
      }
    }
    __syncthreads();

    // cooperative fallback for overflow rows (rare): 2 codes/thread, exact
    for (int r = 0; r < TM; ++r) {
      if (cnt[r] > CAP) {
        const float* xp = &residF[r][0];
        const float a = av_s[r];
        float d1 = np_dist_f4(xp, cb + (size_t)tid * DIMD, a, bK[tid]);
        float d2 = np_dist_f4(xp, cb + (size_t)(tid + 512) * DIMD, a, bK[tid + 512]);
        int i1 = tid;
        if (d2 < d1) { d1 = d2; i1 = tid + 512; }  // strict <: lower idx on tie
        #pragma unroll
        for (int off = 32; off; off >>= 1) {
          float vd = __shfl_xor(d1, off, 64);
          int vi = __shfl_xor(i1, off, 64);
          if (vd < d1 || (vd == d1 && vi < i1)) { d1 = vd; i1 = vi; }
        }
        if (lane == 0) { fwD[wv] = d1; fwI[wv] = i1; }
        __syncthreads();
        if (tid == 0) {
          float bd = fwD[0];
          int bi = fwI[0];
          #pragma unroll
          for (int w = 1; w < NW; ++w) {
            if (fwD[w] < bd || (fwD[w] == bd && fwI[w] < bi)) {
              bd = fwD[w]; bi = fwI[w];
            }
          }
          bcode[r] = bi;
        }
        __syncthreads();
      }
    }

    if (tid < TM) {
      if (cnt[tid] <= CAP) {
        float bd = 3.4e38f;
        int bi = 0x7fffffff;
        for (int ci = 0; ci < cnt[tid]; ++ci) {
          float d = dcD[tid][ci];
          int code = candL[tid][ci];
          if (d < bd || (d == bd && code < bi)) { bd = d; bi = code; }
        }
        bcode[tid] = bi;
      }
      idx_out[(size_t)qi * MM + rowBase + tid] = (float)bcode[tid];
    }
    __syncthreads();

    // STE update — FROZEN: t=fl(q-r); u=fl(r+t); r'=fl(r-u)  (in-LDS now)
    const int codeB = bcode[r32];
    double lsum = 0.0;
    #pragma unroll
    for (int h = 0; h < 2; ++h) {
      const int d = d0 + h * 4;
      const float4 ev = *(const float4*)(cb + (size_t)codeB * DIMD + d);
      const float4 rv = *(const float4*)&residF[r32][d];
      float t0 = __fsub_rn(ev.x, rv.x), u0 = __fadd_rn(rv.x, t0);
      float t1 = __fsub_rn(ev.y, rv.y), u1 = __fadd_rn(rv.y, t1);
      float t2 = __fsub_rn(ev.z, rv.z), u2 = __fadd_rn(rv.z, t2);
      float t3 = __fsub_rn(ev.w, rv.w), u3 = __fadd_rn(rv.w, t3);
      *(float4*)&residF[r32][d] =
          make_float4(__fsub_rn(rv.x, u0), __fsub_rn(rv.y, u1),
                      __fsub_rn(rv.z, u2), __fsub_rn(rv.w, u3));
      lsum += (double)__fmul_rn(t0, t0) + (double)__fmul_rn(t1, t1) +
              (double)__fmul_rn(t2, t2) + (double)__fmul_rn(t3, t3);
    }
    #pragma unroll
    for (int off = 32; off; off >>= 1) lsum += __shfl_xor(lsum, off, 64);
    if (lane == 0) lossW[wv] = lsum;
    __syncthreads();   // also orders residF writes before next stage's reads
    if (tid == 0) {
      double s = 0.0;
      #pragma unroll
      for (int w = 0; w < NW; ++w) s += lossW[w];
      atomicAdd(loss64 + qi, s);
    }
  }

  // epilogue: out_q = fl(x - resid_final)  (same op as k_final; same thread
  // wrote these residF lanes in the last STE, barrier above orders the rest)
  {
    const float* xp = x + (size_t)(rowBase + r32) * DIMD + d0;
    float* op = out_q + (size_t)(rowBase + r32) * DIMD + d0;
    const float4 a0 = *(const float4*)xp;
    const float4 a1 = *(const float4*)(xp + 4);
    const float4 b0 = *(const float4*)&residF[r32][d0];
    const float4 b1 = *(const float4*)&residF[r32][d0 + 4];
    *(float4*)op = make_float4(__fsub_rn(a0.x, b0.x), __fsub_rn(a0.y, b0.y),
                               __fsub_rn(a0.z, b0.z), __fsub_rn(a0.w, b0.w));
    *(float4*)(op + 4) = make_float4(__fsub_rn(a1.x, b1.x), __fsub_rn(a1.y, b1.y),
                                     __fsub_rn(a1.z, b1.z), __fsub_rn(a1.w, b1.w));
  }
}

__global__ __launch_bounds__(64) void k_loss(const double* __restrict__ loss64,
                                             float* __restrict__ out_loss) {
  if (threadIdx.x < QQ)
    out_loss[threadIdx.x] =
        (float)(loss64[threadIdx.x] * (1.0 / (double)((size_t)MM * DIMD)));
}

extern "C" void kernel_launch(void* const* d_in, const int* in_sizes, int n_in,
                              void* d_out, int out_size, void* d_ws, size_t ws_size,
                              hipStream_t stream) {
  const float* x = (const float*)d_in[0];        // [8,2048,256]
  const float* cb = (const float*)d_in[1];       // [4,1024,256]
  float* ws = (float*)d_ws;
  unsigned short* cb16 = (unsigned short*)ws;    // 1,048,576 ushort
  float* bK = ws + 524288;
  int* bmaxI = (int*)(ws + 528384);
  double* loss64 = (double*)(ws + 528390);

  float* out = (float*)d_out;
  float* out_idx = out + (size_t)MM * DIMD;      // 4,194,304
  float* out_loss = out_idx + (size_t)QQ * MM;   // +65,536

  k_cb16<<<dim3(1024), dim3(256), 0, stream>>>(cb, cb16, loss64, bmaxI);
  k_b<<<dim3(QQ * NE * 32 / 256), dim3(256), 0, stream>>>(cb, bK, bmaxI);
  k_fused<<<dim3(MM / TM), dim3(512), 0, stream>>>(x, cb16, cb, bK, bmaxI,
                                                   loss64, out, out_idx);
  k_loss<<<dim3(1), dim3(64), 0, stream>>>(loss64, out_loss);
}

// Round 2
// 390.373 us; speedup vs baseline: 1.6099x; 1.2341x over previous
//
#include <hip/hip_runtime.h>

// ResidualVQ: Q=4, N_EMBED=1024, DIM=256, B=8, S=2048 (fp32).
// out = [quantized 8*2048*256][indices-as-float 4*8*2048][losses 4]
//
// R14: attack the MFMA-phase B-load latency (the shared R12/R13 cost):
//  - TM=32 with M_rep=2: each wave does 2 MFMAs per B-fragment load; grid-wide
//    cb16 traffic halves (512 blocks x 512KB x 4 stages)
//  - per-kc B-batch into a static-indexed register array (8 dwordx4 in flight
//    instead of the 2-3 the 64-VGPR R13 codegen allowed)
//  - bK staged into LDS (sBK) once per stage: d~ / re-rank / fallback reads
//    stop hitting scattered global
//  - residF rows padded +4 floats (row stride 260: kills 256-stride bank alias
//    behind the 3.3M conflict cycles); loss atomic spread over 64 slots
// Certified exact re-rank structure FROZEN (R11-R13): bf16-MFMA prefilter,
// tau margin 8x slack, frozen np fp32 distance chain, tie -> lower index,
// frozen STE recursion. Every frozen op bit-identical to R13 (av tree is
// operand-pairing-identical in the 16-lane distribution).
#define QQ   4
#define NE   1024
#define DIMD 256
#define MM   16384
#define TM   32
#define NW   8      // waves per block (512 threads)
#define CAP  32     // candidate slots per row

typedef short v8s __attribute__((ext_vector_type(8)));   // 8 x bf16
typedef float v4f __attribute__((ext_vector_type(4)));

// ws layout (float offsets):
//  cb16  [QQ][NE][DIMD] ushort @ 0        (524,288 floats)
//  bK    [QQ][NE]              @ 524,288  (4,096)
//  bmaxI int[QQ]               @ 528,384  (4)
//  lossP double[QQ][64]        @ 528,388  (byte 2,113,552 %8==0; 512 floats)

__device__ __forceinline__ unsigned short f2bf(float f) {  // RNE fp32->bf16
  unsigned u = __float_as_uint(f);
  return (unsigned short)((u + 0x7FFFu + ((u >> 16) & 1u)) >> 16);
}

// FROZEN numpy pairwise sumsq of 256 f32, over 32 lanes (k_b). Valid j==0.
__device__ __forceinline__ float np_sumsq_256_x32(const float* __restrict__ p,
                                                  int j) {
  const int bi = j >> 4, L = j & 15;
  const float* q = p + bi * 128 + L;
  float s0 = __fmul_rn(q[0], q[0]);
  float s1 = __fmul_rn(q[16], q[16]);
  float s2 = __fmul_rn(q[32], q[32]);
  float s3 = __fmul_rn(q[48], q[48]);
  float s4 = __fmul_rn(q[64], q[64]);
  float s5 = __fmul_rn(q[80], q[80]);
  float s6 = __fmul_rn(q[96], q[96]);
  float s7 = __fmul_rn(q[112], q[112]);
  float w = __fadd_rn(__fadd_rn(__fadd_rn(s0, s1), __fadd_rn(s2, s3)),
                      __fadd_rn(__fadd_rn(s4, s5), __fadd_rn(s6, s7)));
  float u  = __fadd_rn(w,  __shfl_down(w, 8, 64));   // valid L<8
  float t  = __fadd_rn(u,  __shfl_down(u, 4, 64));   // valid L<4
  float r2 = __fadd_rn(t,  __shfl_down(t, 2, 64));   // valid L<2
  float bb = __fadd_rn(r2, __shfl_down(r2, 1, 64));  // valid L==0 -> blk[bi]
  return __fadd_rn(bb, __shfl_down(bb, 16, 64));     // valid j==0
}

// Same frozen tree over 16 lanes (j=0..15 in a 16-aligned group); bi serial.
// Operand pairing of every __fadd_rn identical to the scalar chain -> bit-exact.
__device__ __forceinline__ float np_sumsq_256_x16(const float* __restrict__ p,
                                                  int j) {
  float blk[2];
  #pragma unroll
  for (int bi = 0; bi < 2; ++bi) {
    const float* q = p + bi * 128 + j;
    float s0 = __fmul_rn(q[0], q[0]);
    float s1 = __fmul_rn(q[16], q[16]);
    float s2 = __fmul_rn(q[32], q[32]);
    float s3 = __fmul_rn(q[48], q[48]);
    float s4 = __fmul_rn(q[64], q[64]);
    float s5 = __fmul_rn(q[80], q[80]);
    float s6 = __fmul_rn(q[96], q[96]);
    float s7 = __fmul_rn(q[112], q[112]);
    float w = __fadd_rn(__fadd_rn(__fadd_rn(s0, s1), __fadd_rn(s2, s3)),
                        __fadd_rn(__fadd_rn(s4, s5), __fadd_rn(s6, s7)));
    float u  = __fadd_rn(w,  __shfl_down(w, 8, 64));   // valid j<8
    float t  = __fadd_rn(u,  __shfl_down(u, 4, 64));   // valid j<4
    float r2 = __fadd_rn(t,  __shfl_down(t, 2, 64));   // valid j<2
    blk[bi]  = __fadd_rn(r2, __shfl_down(r2, 1, 64));  // valid j==0
  }
  return __fadd_rn(blk[0], blk[1]);                    // valid j==0
}

// frozen np distance, float4-load pipelined (IDENTICAL fma sequence/order)
__device__ __forceinline__ float np_dist_f4(const float* __restrict__ xp,
                                            const float* __restrict__ ep,
                                            float a, float b) {
  float m = 0.f;
  #pragma unroll 16
  for (int d4 = 0; d4 < DIMD / 4; ++d4) {
    const float4 xv = *(const float4*)(xp + d4 * 4);
    const float4 ev = *(const float4*)(ep + d4 * 4);
    m = fmaf(xv.x, ev.x, m);
    m = fmaf(xv.y, ev.y, m);
    m = fmaf(xv.z, ev.z, m);
    m = fmaf(xv.w, ev.w, m);
  }
  return __fadd_rn(__fsub_rn(a, __fmul_rn(2.0f, m)), b);
}

// convert all codebooks to bf16 (RNE); block 0 also zero-inits lossP/bmax
__global__ __launch_bounds__(256) void k_cb16(const float* __restrict__ cb,
                                              unsigned short* __restrict__ cb16,
                                              double* __restrict__ lossP,
                                              int* __restrict__ bmaxI) {
  int i = (blockIdx.x * 256 + threadIdx.x) * 4;
  float4 f = *(const float4*)(cb + i);
  unsigned short t[4] = {f2bf(f.x), f2bf(f.y), f2bf(f.z), f2bf(f.w)};
  *(short4*)(cb16 + i) = *(short4*)t;
  if (blockIdx.x == 0) {
    lossP[threadIdx.x] = 0.0;              // QQ*64 == 256 slots exactly
    if (threadIdx.x < QQ) bmaxI[threadIdx.x] = 0;
  }
}

// b_k (frozen np sumsq, 32 lanes/row) + per-stage max
__global__ __launch_bounds__(256) void k_b(const float* __restrict__ cb,
                                           float* __restrict__ bK,
                                           int* __restrict__ bmaxI) {
  int g = blockIdx.x * 256 + threadIdx.x;   // 0 .. QQ*NE*32-1
  int row = g >> 5, j = g & 31;
  float b = np_sumsq_256_x32(cb + (size_t)row * DIMD, j);
  if (j == 0) {
    bK[row] = b;
    atomicMax(bmaxI + (row >> 10), __float_as_int(b));
  }
}

// 512 threads = 8 waves; block owns TM=32 rows through ALL 4 stages.
// Wave w covers codes [w*128,(w+1)*128) as 8 col-tiles x 2 row-tiles (M_rep=2).
__global__ __launch_bounds__(512, 4) void k_fused(
    const float* __restrict__ x,              // [MM][DIMD]
    const unsigned short* __restrict__ cb16a, // [QQ][NE][DIMD] bf16
    const float* __restrict__ cba,            // [QQ][NE][DIMD] fp32
    const float* __restrict__ bKa,            // [QQ][NE]
    const int*   __restrict__ bmaxI,          // [QQ]
    double* __restrict__ lossP,               // [QQ][64]
    float* __restrict__ out_q,                // [MM][DIMD]
    float* __restrict__ idx_out) {            // [QQ][MM] floats
  __shared__ float residF[TM][DIMD + 4];       // fp32 residual, all 4 stages
  __shared__ unsigned short sX[TM][DIMD + 8];  // bf16 rows
  __shared__ float  sBK[NE];                   // bK staged per stage
  __shared__ float  av_s[TM];
  __shared__ float  candD[TM][NW];
  __shared__ float  thrS[TM];
  __shared__ int    cnt[TM];
  __shared__ int    candL[TM][CAP];
  __shared__ float  dcD[TM][CAP];
  __shared__ int    bcode[TM];
  __shared__ float  fwD[NW];
  __shared__ int    fwI[NW];
  __shared__ double lossW[NW];

  const int tid  = threadIdx.x;
  const int lane = tid & 63;
  const int wv   = tid >> 6;
  const int rowBase = blockIdx.x * TM;
  const int r16 = tid >> 4;        // row 0..31 (16 threads per row)
  const int j16 = tid & 15;        // lane in row-group
  const int d0  = j16 * 16;        // 16 floats per thread per row
  const int m16  = lane & 15;
  const int quad = lane >> 4;

  // x -> residF (exact fp32; stage-0 residual == x)
  {
    const float* xp = x + (size_t)(rowBase + r16) * DIMD + d0;
    #pragma unroll
    for (int h = 0; h < 4; ++h)
      *(float4*)&residF[r16][d0 + h * 4] = *(const float4*)(xp + h * 4);
  }
  __syncthreads();

  #pragma unroll 1
  for (int qi = 0; qi < QQ; ++qi) {
    const unsigned short* cb16 = cb16a + (size_t)qi * NE * DIMD;
    const float* cb = cba + (size_t)qi * NE * DIMD;
    const float* bK = bKa + (size_t)qi * NE;
    const float bmx = __int_as_float(bmaxI[qi]);

    // av (FROZEN, 16-lane tree, from LDS) + cnt reset + bK->LDS + bf16 staging
    {
      float av = np_sumsq_256_x16(&residF[r16][0], j16);
      if (j16 == 0) av_s[r16] = av;
    }
    if (tid < TM) cnt[tid] = 0;
    sBK[tid] = bK[tid];
    sBK[tid + 512] = bK[tid + 512];
    {
      #pragma unroll
      for (int h = 0; h < 2; ++h) {
        const float* rp = &residF[r16][d0 + h * 8];
        const float4 f0 = *(const float4*)rp;
        const float4 f1 = *(const float4*)(rp + 4);
        unsigned short t[8] = {f2bf(f0.x), f2bf(f0.y), f2bf(f0.z), f2bf(f0.w),
                               f2bf(f1.x), f2bf(f1.y), f2bf(f1.z), f2bf(f1.w)};
        *(v8s*)&sX[r16][d0 + h * 8] = *(v8s*)t;
      }
    }
    __syncthreads();

    // MFMA: M~[row][code], 2 row-tiles x 8 col-tiles per wave.
    // Per kc: batch all 8 B-fragments into registers (8 dwordx4 in flight),
    // then 16 MFMAs (2 per B-fragment).
    v4f acc[2][8];
    #pragma unroll
    for (int mt = 0; mt < 2; ++mt)
      #pragma unroll
      for (int ct = 0; ct < 8; ++ct) acc[mt][ct] = (v4f)(0.f);
    const unsigned short* bptr =
        cb16 + ((size_t)(wv * 128 + m16)) * DIMD + quad * 8;
    #pragma unroll
    for (int kc = 0; kc < 8; ++kc) {
      v8s bfr[8];
      #pragma unroll
      for (int ct = 0; ct < 8; ++ct)
        bfr[ct] = *(const v8s*)(bptr + (size_t)ct * 16 * DIMD + kc * 32);
      v8s a0 = *(const v8s*)&sX[m16][kc * 32 + quad * 8];
      v8s a1 = *(const v8s*)&sX[16 + m16][kc * 32 + quad * 8];
      #pragma unroll
      for (int ct = 0; ct < 8; ++ct) {
        acc[0][ct] = __builtin_amdgcn_mfma_f32_16x16x32_bf16(a0, bfr[ct], acc[0][ct], 0, 0, 0);
        acc[1][ct] = __builtin_amdgcn_mfma_f32_16x16x32_bf16(a1, bfr[ct], acc[1][ct], 0, 0, 0);
      }
    }

    // approx dist in-place: d~ = a - 2*M~ + b  (D: row=mt*16+quad*4+v, col=m16)
    float av8[2][4];
    #pragma unroll
    for (int mt = 0; mt < 2; ++mt)
      #pragma unroll
      for (int v = 0; v < 4; ++v) av8[mt][v] = av_s[mt * 16 + quad * 4 + v];
    #pragma unroll
    for (int ct = 0; ct < 8; ++ct) {
      const float bv = sBK[wv * 128 + ct * 16 + m16];
      #pragma unroll
      for (int mt = 0; mt < 2; ++mt)
        #pragma unroll
        for (int v = 0; v < 4; ++v)
          acc[mt][ct][v] = av8[mt][v] - 2.0f * acc[mt][ct][v] + bv;
    }

    // per-row min: over ct, then across the 16 lanes of each quad
    #pragma unroll
    for (int mt = 0; mt < 2; ++mt) {
      float vmin[4];
      #pragma unroll
      for (int v = 0; v < 4; ++v) {
        vmin[v] = acc[mt][0][v];
        #pragma unroll
        for (int ct = 1; ct < 8; ++ct) vmin[v] = fminf(vmin[v], acc[mt][ct][v]);
        #pragma unroll
        for (int off = 1; off < 16; off <<= 1)
          vmin[v] = fminf(vmin[v], __shfl_xor(vmin[v], off, 64));
      }
      if (m16 == 0) {
        #pragma unroll
        for (int v = 0; v < 4; ++v) candD[mt * 16 + quad * 4 + v][wv] = vmin[v];
      }
    }
    __syncthreads();
    if (tid < TM) {
      float bd = candD[tid][0];
      #pragma unroll
      for (int w = 1; w < NW; ++w) bd = fminf(bd, candD[tid][w]);
      // certified margin: 2*2^-8*sqrt(a*bmax) needed; 2^-5*sqrt(.)+0.1 = 8x slack
      thrS[tid] = bd + 0.03125f * sqrtf(av_s[tid] * bmx) + 0.1f;
    }
    __syncthreads();

    // gather candidates
    #pragma unroll
    for (int ct = 0; ct < 8; ++ct) {
      const int code = wv * 128 + ct * 16 + m16;
      #pragma unroll
      for (int mt = 0; mt < 2; ++mt) {
        #pragma unroll
        for (int v = 0; v < 4; ++v) {
          const int row = mt * 16 + quad * 4 + v;
          if (acc[mt][ct][v] <= thrS[row]) {
            int pos = atomicAdd(&cnt[row], 1);
            if (pos < CAP) candL[row][pos] = code;
          }
        }
      }
    }
    __syncthreads();

    // exact (frozen) distance per candidate: thread (row, j16) covers slots
    // j16 and j16+16 (x from LDS: identical fp32 values, identical fma order)
    {
      const int n = (cnt[r16] <= CAP) ? cnt[r16] : 0;  // overflow -> fallback
      if (j16 < n) {
        const int code = candL[r16][j16];
        dcD[r16][j16] = np_dist_f4(&residF[r16][0], cb + (size_t)code * DIMD,
                                   av_s[r16], sBK[code]);
      }
      if (j16 + 16 < n) {
        const int code = candL[r16][j16 + 16];
        dcD[r16][j16 + 16] = np_dist_f4(&residF[r16][0], cb + (size_t)code * DIMD,
                                        av_s[r16], sBK[code]);
      }
    }
    __syncthreads();

    // cooperative fallback for overflow rows (rare): 2 codes/thread, exact
    for (int r = 0; r < TM; ++r) {
      if (cnt[r] > CAP) {
        const float* xp = &residF[r][0];
        const float a = av_s[r];
        float d1 = np_dist_f4(xp, cb + (size_t)tid * DIMD, a, sBK[tid]);
        float d2 = np_dist_f4(xp, cb + (size_t)(tid + 512) * DIMD, a, sBK[tid + 512]);
        int i1 = tid;
        if (d2 < d1) { d1 = d2; i1 = tid + 512; }  // strict <: lower idx on tie
        #pragma unroll
        for (int off = 32; off; off >>= 1) {
          float vd = __shfl_xor(d1, off, 64);
          int vi = __shfl_xor(i1, off, 64);
          if (vd < d1 || (vd == d1 && vi < i1)) { d1 = vd; i1 = vi; }
        }
        if (lane == 0) { fwD[wv] = d1; fwI[wv] = i1; }
        __syncthreads();
        if (tid == 0) {
          float bd = fwD[0];
          int bi = fwI[0];
          #pragma unroll
          for (int w = 1; w < NW; ++w) {
            if (fwD[w] < bd || (fwD[w] == bd && fwI[w] < bi)) {
              bd = fwD[w]; bi = fwI[w];
            }
          }
          bcode[r] = bi;
        }
        __syncthreads();
      }
    }

    if (tid < TM) {
      if (cnt[tid] <= CAP) {
        float bd = 3.4e38f;
        int bi = 0x7fffffff;
        for (int ci = 0; ci < cnt[tid]; ++ci) {
          float d = dcD[tid][ci];
          int code = candL[tid][ci];
          if (d < bd || (d == bd && code < bi)) { bd = d; bi = code; }
        }
        bcode[tid] = bi;
      }
      idx_out[(size_t)qi * MM + rowBase + tid] = (float)bcode[tid];
    }
    __syncthreads();

    // STE update — FROZEN: t=fl(q-r); u=fl(r+t); r'=fl(r-u)  (in-LDS)
    const int codeB = bcode[r16];
    double lsum = 0.0;
    #pragma unroll
    for (int h = 0; h < 4; ++h) {
      const int d = d0 + h * 4;
      const float4 ev = *(const float4*)(cb + (size_t)codeB * DIMD + d);
      const float4 rv = *(const float4*)&residF[r16][d];
      float t0 = __fsub_rn(ev.x, rv.x), u0 = __fadd_rn(rv.x, t0);
      float t1 = __fsub_rn(ev.y, rv.y), u1 = __fadd_rn(rv.y, t1);
      float t2 = __fsub_rn(ev.z, rv.z), u2 = __fadd_rn(rv.z, t2);
      float t3 = __fsub_rn(ev.w, rv.w), u3 = __fadd_rn(rv.w, t3);
      *(float4*)&residF[r16][d] =
          make_float4(__fsub_rn(rv.x, u0), __fsub_rn(rv.y, u1),
                      __fsub_rn(rv.z, u2), __fsub_rn(rv.w, u3));
      lsum += (double)__fmul_rn(t0, t0) + (double)__fmul_rn(t1, t1) +
              (double)__fmul_rn(t2, t2) + (double)__fmul_rn(t3, t3);
    }
    #pragma unroll
    for (int off = 32; off; off >>= 1) lsum += __shfl_xor(lsum, off, 64);
    if (lane == 0) lossW[wv] = lsum;
    __syncthreads();   // also orders residF writes before next stage's reads
    if (tid == 0) {
      double s = 0.0;
      #pragma unroll
      for (int w = 0; w < NW; ++w) s += lossW[w];
      atomicAdd(lossP + (size_t)qi * 64 + (blockIdx.x & 63), s);
    }
  }

  // epilogue: out_q = fl(x - resid_final)  (each thread reads the residF
  // lanes it wrote in the last STE)
  {
    const float* xp = x + (size_t)(rowBase + r16) * DIMD + d0;
    float* op = out_q + (size_t)(rowBase + r16) * DIMD + d0;
    #pragma unroll
    for (int h = 0; h < 4; ++h) {
      const float4 a = *(const float4*)(xp + h * 4);
      const float4 b = *(const float4*)&residF[r16][d0 + h * 4];
      *(float4*)(op + h * 4) =
          make_float4(__fsub_rn(a.x, b.x), __fsub_rn(a.y, b.y),
                      __fsub_rn(a.z, b.z), __fsub_rn(a.w, b.w));
    }
  }
}

__global__ __launch_bounds__(64) void k_loss(const double* __restrict__ lossP,
                                             float* __restrict__ out_loss) {
  if (threadIdx.x < QQ) {
    double s = 0.0;
    for (int i = 0; i < 64; ++i) s += lossP[(size_t)threadIdx.x * 64 + i];
    out_loss[threadIdx.x] = (float)(s * (1.0 / (double)((size_t)MM * DIMD)));
  }
}

extern "C" void kernel_launch(void* const* d_in, const int* in_sizes, int n_in,
                              void* d_out, int out_size, void* d_ws, size_t ws_size,
                              hipStream_t stream) {
  const float* x = (const float*)d_in[0];        // [8,2048,256]
  const float* cb = (const float*)d_in[1];       // [4,1024,256]
  float* ws = (float*)d_ws;
  unsigned short* cb16 = (unsigned short*)ws;    // 1,048,576 ushort
  float* bK = ws + 524288;
  int* bmaxI = (int*)(ws + 528384);
  double* lossP = (double*)(ws + 528388);        // [QQ][64], byte off %8==0

  float* out = (float*)d_out;
  float* out_idx = out + (size_t)MM * DIMD;      // 4,194,304
  float* out_loss = out_idx + (size_t)QQ * MM;   // +65,536

  k_cb16<<<dim3(1024), dim3(256), 0, stream>>>(cb, cb16, lossP, bmaxI);
  k_b<<<dim3(QQ * NE * 32 / 256), dim3(256), 0, stream>>>(cb, bK, bmaxI);
  k_fused<<<dim3(MM / TM), dim3(512), 0, stream>>>(x, cb16, cb, bK, bmaxI,
                                                   lossP, out, out_idx);
  k_loss<<<dim3(1), dim3(64), 0, stream>>>(lossP, out_loss);
}